// Round 5
// baseline (109.127 us; speedup 1.0000x reference)
//
#include <hip/hip_runtime.h>

// NCuts loss: seg [8,4,224,224], padded_seg [8,4,232,232],
// weight [8,1,224,224,9,9], sum_weight [8,1,224,224] -> out[8] (fp32)
//
// stage1: one block per image row (8*224 = 1792 blocks); each block walks its
// 4 tiles of 56 px, software-pipelined: prefetch tile t+1 into registers
// while computing tile t from LDS (single LDS buffer; writes occur only in
// the barrier-bounded window after compute). Tap loop identical to round 4:
// 81 taps split across 4 waves, pure LDS + FMA, conflict-free layouts.

constexpr int NN  = 8;
constexpr int KK  = 4;
constexpr int HH  = 224;
constexpr int WW  = 224;
constexpr int PAD = 4;                   // RADIUS-1
constexpr int HP  = HH + 2 * PAD;        // 232
constexpr int WP  = WW + 2 * PAD;        // 232
constexpr int NWIN = 81;
constexpr int PIX = HH * WW;             // 50176
constexpr int TPB = 256;
constexpr int PPB = 56;                  // pixels per tile
constexpr int TPR = WW / PPB;            // 4 tiles per row
constexpr int BPI = HH * TPR;            // 896 tiles per image (for stage2)
constexpr int PLANE = HP * WP;           // 53824
constexpr int PSG_ROW = 64;              // 56 + 8 window cols, float4-aligned
constexpr int PSG_CLS = 9 * PSG_ROW;     // 576 floats per class tile
constexpr int WF4 = PPB * NWIN / 4;      // 1134 float4 of weight per tile
constexpr int PF4 = KK * PSG_CLS / 4;    // 576 float4 of pseg tile
constexpr int WREG = 5;                  // ceil(1134/256)
constexpr int PREG = 3;                  // ceil(576/256)

template<int T0, int T1>
__device__ inline void do_taps(const float* __restrict__ lwp,
                               const float* __restrict__ psl,
                               float acc[KK]) {
#pragma unroll
    for (int t = T0; t < T1; ++t) {
        const int m = t / 9;
        const int j = t - 9 * m;          // compile-time after unroll
        const float wv = lwp[t];          // ds_read_b32, immediate offset
#pragma unroll
        for (int c = 0; c < KK; ++c)
            acc[c] += psl[c * PSG_CLS + m * PSG_ROW + j] * wv;
    }
}

__global__ __launch_bounds__(TPB, 4) void ncuts_stage1(
    const float* __restrict__ seg, const float* __restrict__ pseg,
    const float* __restrict__ wgt, const float* __restrict__ swgt,
    float* __restrict__ part)
{
    const int b   = blockIdx.x;              // n*224 + h
    const int n   = b / HH;
    const int h   = b - n * HH;
    const int tid = threadIdx.x;
    const int wv_ = tid >> 6;
    const int lane = tid & 63;

    __shared__ float lds_w[PPB * NWIN];          // 18144 B
    __shared__ float psg_lds[KK * PSG_CLS];      // 9216 B
    __shared__ float accB[PPB * 17];             // 3808 B

    const size_t nb = (size_t)n * KK * PLANE;

    float4 wreg[WREG];
    float4 preg[PREG];

    // ---- prefetch helper: tile at column w0 -> registers (coalesced f4) ----
    auto load_tile = [&](int w0, float4 (&wr)[WREG], float4 (&pr)[PREG]) {
        const float4* wsrc =
            (const float4*)(wgt + ((size_t)n * PIX + (size_t)h * WW + w0) * NWIN);
#pragma unroll
        for (int k = 0; k < WREG; ++k) {
            const int i = tid + k * TPB;
            if (i < WF4) wr[k] = wsrc[i];
        }
#pragma unroll
        for (int k = 0; k < PREG; ++k) {
            const int i = tid + k * TPB;
            if (i < PF4) {
                const int c  = i / (PSG_CLS / 4);
                const int r  = i - c * (PSG_CLS / 4);
                const int m  = r / (PSG_ROW / 4);
                const int c4 = r - m * (PSG_ROW / 4);
                pr[k] = *(const float4*)(pseg + nb + (size_t)c * PLANE +
                                         (size_t)(h + m) * WP + w0 + c4 * 4);
            }
        }
    };

    load_tile(0, wreg, preg);

#pragma unroll
    for (int tt = 0; tt < TPR; ++tt) {
        const int w0 = tt * PPB;

        // ---- A: registers -> LDS (implicit vmcnt wait on the prefetch) ----
        {
            float4* wdst = (float4*)lds_w;
#pragma unroll
            for (int k = 0; k < WREG; ++k) {
                const int i = tid + k * TPB;
                if (i < WF4) wdst[i] = wreg[k];
            }
            float4* pdst = (float4*)psg_lds;
#pragma unroll
            for (int k = 0; k < PREG; ++k) {
                const int i = tid + k * TPB;
                if (i < PF4) pdst[i] = preg[k];
            }
        }
        __syncthreads();                       // B: tile visible to all waves

        // ---- C: issue next tile's loads (latency hides under compute) ----
        if (tt + 1 < TPR) load_tile(w0 + PPB, wreg, preg);

        // ---- D: compute from LDS (round-4 tap loop) ----
        float acc[KK] = {0.f, 0.f, 0.f, 0.f};
        if (lane < PPB) {
            const float* lwp = lds_w + lane * NWIN;
            const float* psl = psg_lds + lane;
            switch (wv_) {
                case 0:  do_taps<0, 20>(lwp, psl, acc); break;
                case 1:  do_taps<20, 40>(lwp, psl, acc); break;
                case 2:  do_taps<40, 60>(lwp, psl, acc); break;
                default: do_taps<60, 81>(lwp, psl, acc); break;
            }
#pragma unroll
            for (int c = 0; c < KK; ++c) accB[lane * 17 + wv_ * 4 + c] = acc[c];
        }
        __syncthreads();                       // B_e: accB visible; buf free

        // ---- epilogue: wave c owns class c; lanes = pixels ----
        const int c = wv_;
        float A = 0.f, V = 0.f;
        if (lane < PPB) {
            const int p = h * WW + w0 + lane;
            const float r = accB[lane * 17 + c]     + accB[lane * 17 + 4 + c] +
                            accB[lane * 17 + 8 + c] + accB[lane * 17 + 12 + c];
            const float sv  = seg[(size_t)n * KK * PIX + (size_t)c * PIX + p];
            const float swv = swgt[(size_t)n * PIX + p];
            A = r * sv;
            V = swv * sv;
        }
#pragma unroll
        for (int off = 32; off > 0; off >>= 1) {
            A += __shfl_down(A, off, 64);
            V += __shfl_down(V, off, 64);
        }
        if (lane == 0) {
            const size_t tg = (size_t)(n * HH + h) * TPR + tt;   // = n*896 + h*4 + tt
            part[tg * 8 + c]     = A;
            part[tg * 8 + 4 + c] = V;
        }
        // next iteration's barrier B orders accB/buf reuse; no extra barrier
    }
}

__global__ __launch_bounds__(TPB) void ncuts_stage2(
    const float* __restrict__ part, float* __restrict__ out)
{
    const int n   = blockIdx.x;
    const int tid = threadIdx.x;

    float vals[8] = {0.f, 0.f, 0.f, 0.f, 0.f, 0.f, 0.f, 0.f};
    for (int b = tid; b < BPI; b += TPB) {
        const float* q = part + ((size_t)(n * BPI + b)) * 8;
#pragma unroll
        for (int i = 0; i < 8; ++i) vals[i] += q[i];
    }

    __shared__ float lred[4][8];
    const int lane = tid & 63;
    const int wv_  = tid >> 6;
#pragma unroll
    for (int i = 0; i < 8; ++i) {
        float v = vals[i];
#pragma unroll
        for (int off = 32; off > 0; off >>= 1) v += __shfl_down(v, off, 64);
        if (lane == 0) lred[wv_][i] = v;
    }
    __syncthreads();
    if (tid == 0) {
        float assoc = 0.f;
#pragma unroll
        for (int k = 0; k < 4; ++k) {
            const float A = lred[0][k] + lred[1][k] + lred[2][k] + lred[3][k];
            const float V = lred[0][4 + k] + lred[1][4 + k] + lred[2][4 + k] + lred[3][4 + k];
            assoc += A / V;
        }
        out[n] = 4.0f - assoc;
    }
}

extern "C" void kernel_launch(void* const* d_in, const int* in_sizes, int n_in,
                              void* d_out, int out_size, void* d_ws, size_t ws_size,
                              hipStream_t stream) {
    const float* seg  = (const float*)d_in[0];
    const float* pseg = (const float*)d_in[1];
    const float* wgt  = (const float*)d_in[2];
    const float* swgt = (const float*)d_in[3];
    float* out  = (float*)d_out;
    float* part = (float*)d_ws;   // 7168 tiles * 8 floats = 229376 B

    ncuts_stage1<<<NN * HH, TPB, 0, stream>>>(seg, pseg, wgt, swgt, part);
    ncuts_stage2<<<NN, TPB, 0, stream>>>(part, out);
}

// Round 6
// 48.617 us; speedup vs baseline: 2.2446x; 2.2446x over previous
//
#include <hip/hip_runtime.h>

// NCuts loss: seg [8,4,224,224], padded_seg [8,4,232,232],
// weight [8,1,224,224,9,9], sum_weight [8,1,224,224] -> out[8] (fp32)
//
// stage1: one persistent block per image row (8*224 = 1792 blocks).
//  - psg tile for the whole row ([4 classes][9 rows][232 cols], 33.4 KB)
//    staged ONCE per block via global_load_lds.
//  - weight slab double-buffered (2 x 56px*81 = 2 x 18.1 KB), prefetched one
//    tile ahead via global_load_lds (zero VGPR round-trip -> no spills).
//    Prefetch issued at loop top; __syncthreads() AFTER compute drains vmcnt,
//    so HBM latency hides under the ~2.3k-cycle tap loop.
//  - tap loop identical to round 4 (proven): 81 taps split across 4 waves,
//    pure LDS + FMA, conflict-free layouts.

constexpr int NN  = 8;
constexpr int KK  = 4;
constexpr int HH  = 224;
constexpr int WW  = 224;
constexpr int PAD = 4;                   // RADIUS-1
constexpr int HP  = HH + 2 * PAD;        // 232
constexpr int WP  = WW + 2 * PAD;        // 232
constexpr int NWIN = 81;
constexpr int PIX = HH * WW;             // 50176
constexpr int TPB = 256;
constexpr int PPB = 56;                  // pixels per tile
constexpr int TPR = WW / PPB;            // 4 tiles per row
constexpr int BPI = HH * TPR;            // 896 tiles per image (stage2)
constexpr int PLANE = HP * WP;           // 53824
constexpr int PSG_CLS = 9 * WP;          // 2088 floats per class row-tile
constexpr int PSGF4 = KK * PSG_CLS / 4;  // 2088 float4
constexpr int WSLAB = PPB * NWIN;        // 4536 floats per weight tile
constexpr int WF4 = WSLAB / 4;           // 1134 float4

#define GLL16(gptr, lptr)                                            \
    __builtin_amdgcn_global_load_lds(                                \
        (const __attribute__((address_space(1))) void*)(gptr),       \
        (__attribute__((address_space(3))) void*)(lptr), 16, 0, 0)

template<int T0, int T1>
__device__ inline void do_taps(const float* __restrict__ lwp,
                               const float* __restrict__ psl,
                               float acc[KK]) {
#pragma unroll
    for (int t = T0; t < T1; ++t) {
        const int m = t / 9;
        const int j = t - 9 * m;          // compile-time after unroll
        const float wv = lwp[t];          // ds_read_b32, immediate offset
#pragma unroll
        for (int c = 0; c < KK; ++c)
            acc[c] += psl[c * PSG_CLS + m * WP + j] * wv;
    }
}

__global__ __launch_bounds__(TPB) void ncuts_stage1(
    const float* __restrict__ seg, const float* __restrict__ pseg,
    const float* __restrict__ wgt, const float* __restrict__ swgt,
    float* __restrict__ part)
{
    const int b    = blockIdx.x;             // n*224 + h
    const int n    = b / HH;
    const int h    = b - n * HH;
    const int tid  = threadIdx.x;
    const int wv_  = tid >> 6;
    const int lane = tid & 63;

    __shared__ float lds_w[2 * WSLAB];       // 36288 B (double buffer)
    __shared__ float psg_lds[KK * PSG_CLS];  // 33408 B (whole row, all classes)
    __shared__ float accB[PPB * 17];         // 3808 B, stride 17 -> no conflicts

    // ---- weight tile stager: global_load_lds, linear LDS dest ----
    auto stage_w = [&](int buf, int tt) {
        const float4* wsrc = (const float4*)(
            wgt + ((size_t)n * PIX + (size_t)h * WW + tt * PPB) * NWIN);
        float* base = lds_w + buf * WSLAB;
#pragma unroll
        for (int k = 0; k < 5; ++k) {
            const int i = k * TPB + tid;
            if (i < WF4)
                GLL16(wsrc + i, base + ((k * TPB + (tid >> 6) * 64) << 2));
        }
    };

    // ---- prologue: psg row-tile (once) + weight tile 0 ----
    {
        const size_t nb = (size_t)n * KK * PLANE;
#pragma unroll
        for (int k = 0; k < 9; ++k) {
            const int i = k * TPB + tid;
            if (i < PSGF4) {
                const int c  = i / 522;          // 522 = PSG_CLS/4
                const int r  = i - 522 * c;
                const int m  = r / 58;           // 58 = WP/4
                const int c4 = r - 58 * m;
                const float* src = pseg + nb + (size_t)c * PLANE +
                                   (size_t)(h + m) * WP + c4 * 4;
                GLL16(src, psg_lds + ((k * TPB + (tid >> 6) * 64) << 2));
            }
        }
    }
    stage_w(0, 0);

    // ---- hoist seg / sum_weight for all 4 tiles into registers ----
    const int cc = wv_;                      // epilogue class of this wave
    float segv[TPR] = {0.f, 0.f, 0.f, 0.f};
    float swv[TPR]  = {0.f, 0.f, 0.f, 0.f};
    if (lane < PPB) {
#pragma unroll
        for (int tt = 0; tt < TPR; ++tt) {
            const int p = h * WW + tt * PPB + lane;
            segv[tt] = seg[(size_t)n * KK * PIX + (size_t)cc * PIX + p];
            swv[tt]  = swgt[(size_t)n * PIX + p];
        }
    }

    __syncthreads();   // drains vmcnt: psg row + weight tile 0 landed

    int cur = 0;
#pragma unroll
    for (int tt = 0; tt < TPR; ++tt) {
        // ---- async prefetch of next weight tile into the other buffer ----
        if (tt + 1 < TPR) stage_w(cur ^ 1, tt + 1);

        // ---- compute tile tt from LDS (round-4 tap loop) ----
        float acc[KK] = {0.f, 0.f, 0.f, 0.f};
        if (lane < PPB) {
            const float* lwp = lds_w + cur * WSLAB + lane * NWIN;
            const float* psl = psg_lds + tt * PPB + lane;
            switch (wv_) {
                case 0:  do_taps<0, 20>(lwp, psl, acc); break;
                case 1:  do_taps<20, 40>(lwp, psl, acc); break;
                case 2:  do_taps<40, 60>(lwp, psl, acc); break;
                default: do_taps<60, 81>(lwp, psl, acc); break;
            }
#pragma unroll
            for (int c = 0; c < KK; ++c) accB[lane * 17 + wv_ * 4 + c] = acc[c];
        }
        __syncthreads();   // accB visible; prefetch vmcnt drained (hidden under compute)

        // ---- epilogue: wave cc owns class cc; lanes = pixels ----
        float A = 0.f, V = 0.f;
        if (lane < PPB) {
            const float r = accB[lane * 17 + cc]     + accB[lane * 17 + 4 + cc] +
                            accB[lane * 17 + 8 + cc] + accB[lane * 17 + 12 + cc];
            A = r * segv[tt];
            V = swv[tt] * segv[tt];
        }
#pragma unroll
        for (int off = 32; off > 0; off >>= 1) {
            A += __shfl_down(A, off, 64);
            V += __shfl_down(V, off, 64);
        }
        if (lane == 0) {
            const size_t tg = (size_t)b * TPR + tt;   // (n*224+h)*4+tt
            part[tg * 8 + cc]     = A;
            part[tg * 8 + 4 + cc] = V;
        }
        __syncthreads();   // epilogue accB reads done before next tile rewrites
        cur ^= 1;
    }
}

__global__ __launch_bounds__(TPB) void ncuts_stage2(
    const float* __restrict__ part, float* __restrict__ out)
{
    const int n   = blockIdx.x;
    const int tid = threadIdx.x;

    float vals[8] = {0.f, 0.f, 0.f, 0.f, 0.f, 0.f, 0.f, 0.f};
    for (int bb = tid; bb < BPI; bb += TPB) {
        const float* q = part + ((size_t)(n * BPI + bb)) * 8;
#pragma unroll
        for (int i = 0; i < 8; ++i) vals[i] += q[i];
    }

    __shared__ float lred[4][8];
    const int lane = tid & 63;
    const int wv_  = tid >> 6;
#pragma unroll
    for (int i = 0; i < 8; ++i) {
        float v = vals[i];
#pragma unroll
        for (int off = 32; off > 0; off >>= 1) v += __shfl_down(v, off, 64);
        if (lane == 0) lred[wv_][i] = v;
    }
    __syncthreads();
    if (tid == 0) {
        float assoc = 0.f;
#pragma unroll
        for (int k = 0; k < 4; ++k) {
            const float A = lred[0][k] + lred[1][k] + lred[2][k] + lred[3][k];
            const float V = lred[0][4 + k] + lred[1][4 + k] + lred[2][4 + k] + lred[3][4 + k];
            assoc += A / V;
        }
        out[n] = 4.0f - assoc;
    }
}

extern "C" void kernel_launch(void* const* d_in, const int* in_sizes, int n_in,
                              void* d_out, int out_size, void* d_ws, size_t ws_size,
                              hipStream_t stream) {
    const float* seg  = (const float*)d_in[0];
    const float* pseg = (const float*)d_in[1];
    const float* wgt  = (const float*)d_in[2];
    const float* swgt = (const float*)d_in[3];
    float* out  = (float*)d_out;
    float* part = (float*)d_ws;   // 7168 tiles * 8 floats = 229376 B

    ncuts_stage1<<<NN * HH, TPB, 0, stream>>>(seg, pseg, wgt, swgt, part);
    ncuts_stage2<<<NN, TPB, 0, stream>>>(part, out);
}